// Round 5
// baseline (624.171 us; speedup 1.0000x reference)
//
#include <hip/hip_runtime.h>

// ---------------------------------------------------------------------------
// QRNN: h_{t+1} = sigmoid(W_out @ circuit(W_in @ [h;x_t] + b_in) + b_out)
//
// Circuit reduction: z_k(y) = <psi(y)| U^dag Z_k U |psi(y)> with U fixed.
// psi(y) = prod-state with per-qubit rho = (I - sin(y) Y + cos(y) Z)/2.
// => z_k = sum_{a in {I,Z,Y}^4} C[k][a] * prod_q g(a_q, y_q),
//    g(I)=1, g(Z)=cos y, g(Y)=sin y  (the -1 per Y is folded into C).
// C (4 x 81, digit q of a = base-3 digit 3^q; qubit q) built by qrnn_precompute.
//
// Main kernel mapping: 16 lanes per sample (4 samples per wave64).
//   sl = lane & 15. Lane owns h[sl + 16j], j=0..7, and x_t[4sl..4sl+3].
//   reduce1 (y): fold to comp g=sl&3 (3 DS) + butterfly xor4,8 (2 DS),
//                then 4 absolute-lane gathers -> y0..y3 per lane.
//   z: Horner contraction. Lane (k=sl&3, grp=sl>>2) evaluates
//      g(grp,y3) * sum_{d2} g2 sum_{d1} g1 sum_{d0} g0 C[k][27 grp + ...]
//      (29 straight-line FMAs, no selects in inner tree); grp==3 idle.
//   reduce2 (z): butterfly xor4,8 (2 DS) + 4 gathers.
//   2-step register prefetch pipeline on x (float4 per lane per step).
//
// NOTE: no min-waves launch_bounds arg — persistent state ~135 VGPR + temps
// ≈ 160 VGPR; a (256,2) bound would cap at 128 and spill in the hot loop.
// ---------------------------------------------------------------------------

struct Cpx { float x, y; };
__device__ __forceinline__ Cpx cmul(Cpx a, Cpx b){ return {a.x*b.x - a.y*b.y, a.x*b.y + a.y*b.x}; }
__device__ __forceinline__ Cpx cadd(Cpx a, Cpx b){ return {a.x + b.x, a.y + b.y}; }

__global__ void qrnn_precompute(const float* __restrict__ qw, float* __restrict__ C)
{
    __shared__ Cpx U[16][16];
    __shared__ Cpx M[4][16][16];
    const int tid = threadIdx.x;

    if (tid == 0) {
        for (int i = 0; i < 16; ++i)
            for (int j = 0; j < 16; ++j)
                U[i][j] = Cpx{(i == j) ? 1.f : 0.f, 0.f};

        for (int l = 0; l < 2; ++l) {
            // per-qubit combined rotation A = RX(w) * RZ(w) * RX(w)
            for (int q = 0; q < 4; ++q) {
                float w  = qw[l*4 + q];
                float ch = cosf(0.5f*w), sh = sinf(0.5f*w);
                Cpx RX[2][2] = {{{ch,0.f},{0.f,-sh}},{{0.f,-sh},{ch,0.f}}};
                Cpx RZ[2][2] = {{{ch,-sh},{0.f,0.f}},{{0.f,0.f},{ch,sh}}};
                Cpx T[2][2], A[2][2];
                for (int i = 0; i < 2; ++i)
                    for (int j = 0; j < 2; ++j) {
                        Cpx s{0.f,0.f};
                        for (int k = 0; k < 2; ++k) s = cadd(s, cmul(RZ[i][k], RX[k][j]));
                        T[i][j] = s;
                    }
                for (int i = 0; i < 2; ++i)
                    for (int j = 0; j < 2; ++j) {
                        Cpx s{0.f,0.f};
                        for (int k = 0; k < 2; ++k) s = cadd(s, cmul(RX[i][k], T[k][j]));
                        A[i][j] = s;
                    }
                int bit = 1 << (3 - q);
                for (int r = 0; r < 16; ++r) {
                    if (r & bit) continue;
                    int r1 = r | bit;
                    for (int j = 0; j < 16; ++j) {
                        Cpx a0 = U[r][j], a1 = U[r1][j];
                        U[r][j]  = cadd(cmul(A[0][0], a0), cmul(A[0][1], a1));
                        U[r1][j] = cadd(cmul(A[1][0], a0), cmul(A[1][1], a1));
                    }
                }
            }
            // entangler: CNOT(c,t) RZ(th,t) CNOT(c,t) == diagonal phase:
            // e^{-i th/2} if bit_c==bit_t else e^{+i th/2}
            for (int e = 0; e < 4; ++e) {
                int c = e, t = (e + 1) & 3;
                float th = qw[l*4 + t];
                float ch = cosf(0.5f*th), sh = sinf(0.5f*th);
                Cpx pe{ch,-sh}, pd{ch,sh};
                int bc = 1 << (3 - c), bt = 1 << (3 - t);
                for (int r = 0; r < 16; ++r) {
                    bool eq = (((r & bc) != 0) == ((r & bt) != 0));
                    Cpx ph = eq ? pe : pd;
                    for (int j = 0; j < 16; ++j) U[r][j] = cmul(ph, U[r][j]);
                }
            }
        }
    }
    __syncthreads();

    // M_k = U^dag Z_k U
    for (int e = tid; e < 4*16*16; e += blockDim.x) {
        int k = e >> 8, i = (e >> 4) & 15, j = e & 15;
        int kb = 1 << (3 - k);
        Cpx s{0.f,0.f};
        for (int m = 0; m < 16; ++m) {
            float sg = (m & kb) ? -1.f : 1.f;
            Cpx um = U[m][i]; um.y = -um.y;        // conj
            Cpx t  = cmul(um, U[m][j]);
            s.x += sg * t.x; s.y += sg * t.y;
        }
        M[k][i][j] = s;
    }
    __syncthreads();

    // C[k][a] = Re Tr(P_a M_k)/16 * (-1)^{#Y}; digit q of a (base 3, 3^q): 0=I,1=Z,2=Y
    for (int e = tid; e < 4*81; e += blockDim.x) {
        int k = e / 81, a = e % 81;
        int d[4], aa = a;
        for (int q = 0; q < 4; ++q) { d[q] = aa % 3; aa /= 3; }
        int ym = 0, ny = 0;
        for (int q = 0; q < 4; ++q) if (d[q] == 2) { ym |= 1 << (3 - q); ++ny; }
        Cpx tr{0.f,0.f};
        for (int i = 0; i < 16; ++i) {
            int j = i ^ ym;                         // P[i][j] nonzero only here
            Cpx p{1.f,0.f};
            for (int q = 0; q < 4; ++q) {
                int bi = (i >> (3 - q)) & 1;
                if (d[q] == 1) { if (bi) { p.x = -p.x; p.y = -p.y; } }
                else if (d[q] == 2) {
                    Cpx f = bi ? Cpx{0.f,1.f} : Cpx{0.f,-1.f};  // sigma_y row bi
                    p = cmul(p, f);
                }
            }
            tr = cadd(tr, cmul(p, M[k][j][i]));
        }
        float val = tr.x * 0.0625f;
        if (ny & 1) val = -val;
        C[k*81 + a] = val;
    }
}

// ---------------------------------------------------------------------------

__global__ __launch_bounds__(256) void qrnn_main(
    const float* __restrict__ x,
    const float* __restrict__ W_in,
    const float* __restrict__ b_in,
    const float* __restrict__ W_out,
    const float* __restrict__ b_out,
    const float* __restrict__ C,
    float* __restrict__ out,
    int B)
{
    const int lane = threadIdx.x & 63;
    const int wv   = threadIdx.x >> 6;
    const int slot = lane >> 4;          // sample within wave
    const int sl   = lane & 15;          // lane within sample group
    const int b    = blockIdx.x * 16 + wv * 4 + slot;
    const int bc   = (b < B) ? b : (B - 1);   // clamp; keep all lanes active

    // ---- init: per-lane constants -----------------------------------------
    // W_in rows (q=0..3, row len 192 = [h(128); x(64)])
    float wa[4][8], wx[4][4];
    #pragma unroll
    for (int q = 0; q < 4; ++q) {
        #pragma unroll
        for (int j = 0; j < 8; ++j) wa[q][j] = W_in[q*192 + sl + 16*j];
        #pragma unroll
        for (int u = 0; u < 4; ++u) wx[q][u] = W_in[q*192 + 128 + 4*sl + u];
    }
    const int kown = sl & 3;             // owned component (y and z)
    const int grp  = sl >> 2;            // d3 group for z-Horner (3 = idle)
    const float bi_own = b_in[kown];

    // z-Horner coefficients: C[kown][27*grp + (d0 + 3 d1 + 9 d2)]
    const int cbase = kown*81 + 27*((grp < 3) ? grp : 2);
    float cc[27];
    #pragma unroll
    for (int m = 0; m < 27; ++m) cc[m] = C[cbase + m];
    const bool zact = (grp < 3);

    // W_out rows r = sl + 16j
    float wo[8][4], bo[8];
    #pragma unroll
    for (int j = 0; j < 8; ++j) {
        #pragma unroll
        for (int k = 0; k < 4; ++k) wo[j][k] = W_out[(sl + 16*j)*4 + k];
        bo[j] = b_out[sl + 16*j];
    }

    // ---- state ------------------------------------------------------------
    float h[8];
    #pragma unroll
    for (int j = 0; j < 8; ++j) h[j] = 0.f;

    const float* __restrict__ xb = x + (size_t)bc * (128*64) + 4*sl;
    float4 xcur = *(const float4*)(xb);          // t = 0
    float4 xnxt = *(const float4*)(xb + 64);     // t = 1

    const int gbase = lane & ~3;                 // quad base for absolute gathers

    for (int t = 0; t < 128; ++t) {
        // prefetch t+2 (clamped)
        const int tp = (t + 2 < 128) ? (t + 2) : 127;
        const float4 xpre = *(const float4*)(xb + tp*64);

        // ---- y partials: y[q] = sum_i Win[q][i] h_i + sum_f Win[q][128+f] x_f
        float p0, p1, p2, p3;
        {
            p0 = wx[0][0]*xcur.x; p1 = wx[1][0]*xcur.x; p2 = wx[2][0]*xcur.x; p3 = wx[3][0]*xcur.x;
            p0 = fmaf(wx[0][1], xcur.y, p0); p1 = fmaf(wx[1][1], xcur.y, p1);
            p2 = fmaf(wx[2][1], xcur.y, p2); p3 = fmaf(wx[3][1], xcur.y, p3);
            p0 = fmaf(wx[0][2], xcur.z, p0); p1 = fmaf(wx[1][2], xcur.z, p1);
            p2 = fmaf(wx[2][2], xcur.z, p2); p3 = fmaf(wx[3][2], xcur.z, p3);
            p0 = fmaf(wx[0][3], xcur.w, p0); p1 = fmaf(wx[1][3], xcur.w, p1);
            p2 = fmaf(wx[2][3], xcur.w, p2); p3 = fmaf(wx[3][3], xcur.w, p3);
            #pragma unroll
            for (int j = 0; j < 8; ++j) {
                p0 = fmaf(wa[0][j], h[j], p0);
                p1 = fmaf(wa[1][j], h[j], p1);
                p2 = fmaf(wa[2][j], h[j], p2);
                p3 = fmaf(wa[3][j], h[j], p3);
            }
        }

        // ---- reduce1: fold to comp kown over the 16-lane group
        {
            const bool o1 = (sl & 1) != 0;
            const bool o2 = (sl & 2) != 0;
            float sendA = o1 ? p0 : p1;
            float a  = (o1 ? p1 : p0) + __shfl_xor(sendA, 1, 64);
            float sendB = o1 ? p2 : p3;
            float bq = (o1 ? p3 : p2) + __shfl_xor(sendB, 1, 64);
            float send2 = o2 ? a : bq;
            float s  = (o2 ? bq : a) + __shfl_xor(send2, 2, 64);
            s += __shfl_xor(s, 4, 64);
            s += __shfl_xor(s, 8, 64);
            p0 = s + bi_own;                      // y_{kown}
        }
        // absolute gathers: y_q lives on lane gbase|q
        const float y0 = __shfl(p0, gbase | 0, 64);
        const float y1 = __shfl(p0, gbase | 1, 64);
        const float y2 = __shfl(p0, gbase | 2, 64);
        const float y3 = __shfl(p0, gbase | 3, 64);

        float s0, c0, s1, c1, s2, c2, s3, c3;
        __sincosf(y0, &s0, &c0);
        __sincosf(y1, &s1, &c1);
        __sincosf(y2, &s2, &c2);
        __sincosf(y3, &s3, &c3);

        // ---- z-Horner: lane's partial of z_{kown} for d3 = grp
        float zp;
        {
            float t0, t1, t2, i0, i1, i2;
            t0 = fmaf(s0, cc[ 2], fmaf(c0, cc[ 1], cc[ 0]));
            t1 = fmaf(s0, cc[ 5], fmaf(c0, cc[ 4], cc[ 3]));
            t2 = fmaf(s0, cc[ 8], fmaf(c0, cc[ 7], cc[ 6]));
            i0 = fmaf(s1, t2, fmaf(c1, t1, t0));
            t0 = fmaf(s0, cc[11], fmaf(c0, cc[10], cc[ 9]));
            t1 = fmaf(s0, cc[14], fmaf(c0, cc[13], cc[12]));
            t2 = fmaf(s0, cc[17], fmaf(c0, cc[16], cc[15]));
            i1 = fmaf(s1, t2, fmaf(c1, t1, t0));
            t0 = fmaf(s0, cc[20], fmaf(c0, cc[19], cc[18]));
            t1 = fmaf(s0, cc[23], fmaf(c0, cc[22], cc[21]));
            t2 = fmaf(s0, cc[26], fmaf(c0, cc[25], cc[24]));
            i2 = fmaf(s1, t2, fmaf(c1, t1, t0));
            const float mid = fmaf(s2, i2, fmaf(c2, i1, i0));
            const float g3v = (grp == 0) ? 1.f : ((grp == 1) ? c3 : s3);
            zp = zact ? g3v * mid : 0.f;
        }

        // ---- reduce2: sum over d3-groups (lanes sharing kown: xor 4, 8)
        zp += __shfl_xor(zp, 4, 64);
        zp += __shfl_xor(zp, 8, 64);
        const float z0 = __shfl(zp, gbase | 0, 64);
        const float z1 = __shfl(zp, gbase | 1, 64);
        const float z2 = __shfl(zp, gbase | 2, 64);
        const float z3 = __shfl(zp, gbase | 3, 64);

        // ---- output proj + sigmoid
        #pragma unroll
        for (int j = 0; j < 8; ++j) {
            float u = fmaf(wo[j][0], z0, fmaf(wo[j][1], z1,
                      fmaf(wo[j][2], z2, fmaf(wo[j][3], z3, bo[j]))));
            h[j] = 1.f / (1.f + __expf(-u));
        }

        xcur = xnxt; xnxt = xpre;
    }

    if (b < B) {
        float* ob = out + (size_t)b * 128 + sl;
        #pragma unroll
        for (int j = 0; j < 8; ++j) ob[16*j] = h[j];
    }
}

extern "C" void kernel_launch(void* const* d_in, const int* in_sizes, int n_in,
                              void* d_out, int out_size, void* d_ws, size_t ws_size,
                              hipStream_t stream)
{
    const float* x     = (const float*)d_in[0];
    const float* W_in  = (const float*)d_in[1];
    const float* b_in  = (const float*)d_in[2];
    const float* qw    = (const float*)d_in[3];
    const float* W_out = (const float*)d_in[4];
    const float* b_out = (const float*)d_in[5];
    float* out = (float*)d_out;
    float* C   = (float*)d_ws;                 // 4*81 floats

    const int B = in_sizes[0] / (128*64);      // 8192

    qrnn_precompute<<<1, 128, 0, stream>>>(qw, C);
    const int blocks = (B + 15) / 16;          // 16 samples per 256-thread block
    qrnn_main<<<blocks, 256, 0, stream>>>(x, W_in, b_in, W_out, b_out, C, out, B);
}

// Round 7
// 506.076 us; speedup vs baseline: 1.2334x; 1.2334x over previous
//
#include <hip/hip_runtime.h>

// ---------------------------------------------------------------------------
// QRNN: h_{t+1} = sigmoid(W_out @ circuit(W_in @ [h;x_t] + b_in) + b_out)
//
// Circuit reduction: z_k(y) = <psi(y)| U^dag Z_k U |psi(y)> with U fixed.
// psi(y) = prod-state with per-qubit rho = (I - sin(y) Y + cos(y) Z)/2.
// => z_k = sum_{a in {I,Z,Y}^4} C[k][a] * prod_q g(a_q, y_q),
//    g(I)=1, g(Z)=cos y, g(Y)=sin y  (the -1 per Y is folded into C).
// C (4 x 81, digit q of a = base-3 digit 3^q) built by qrnn_precompute.
//
// R5 counters: VGPR=76 (compiler re-loaded state), Occupancy 21% (2 waves/
// SIMD), VALUBusy 56% -> latency-bound. R6/R7:
//  * 32 lanes/sample, 2 samples/wave -> 4 waves/SIMD.
//  * state ~90 floats; __launch_bounds__(256,4) caps VGPR at 128.
//  * cross-lane via DPP quad_perm (xor1/xor2/quad-broadcast = VALU) and
//    ds_swizzle (xor4/8/16) -> 6 DS ops/step (was ~20 bpermutes).
//  * precompute parallel: 16 threads simulate U columns in registers.
// ---------------------------------------------------------------------------

struct Cpx { float x, y; };
__device__ __forceinline__ Cpx cmul(Cpx a, Cpx b){ return {a.x*b.x - a.y*b.y, a.x*b.y + a.y*b.x}; }
__device__ __forceinline__ Cpx cadd(Cpx a, Cpx b){ return {a.x + b.x, a.y + b.y}; }

// DPP cross-lane (VALU): CTRL = quad_perm code
template<int CTRL>
__device__ __forceinline__ float fdpp(float v) {
    return __int_as_float(__builtin_amdgcn_update_dpp(
        0, __float_as_int(v), CTRL, 0xF, 0xF, true));
}
// ds_swizzle BitMode: lane' = ((lane & and) | or) ^ xor ; PAT=(xor<<10)|(or<<5)|and
template<int PAT>
__device__ __forceinline__ float fswz(float v) {
    return __int_as_float(__builtin_amdgcn_ds_swizzle(__float_as_int(v), PAT));
}

__global__ void qrnn_precompute(const float* __restrict__ qw, float* __restrict__ C)
{
    __shared__ Cpx U[16][16];
    __shared__ Cpx M[4][16][16];
    const int tid = threadIdx.x;          // 64 threads

    // ---- U columns: thread j<16 applies the circuit to basis state e_j ----
    if (tid < 16) {
        Cpx col[16];
        #pragma unroll
        for (int i = 0; i < 16; ++i) col[i] = Cpx{(i == tid) ? 1.f : 0.f, 0.f};

        for (int l = 0; l < 2; ++l) {
            // A = RX(w) * RZ(w) * RX(w) applied on qubit q (BIT = 1<<(3-q))
            #define APPLY_Q(qq, BIT)                                             \
            {                                                                    \
                const float w  = qw[l*4 + (qq)];                                 \
                const float ch = cosf(0.5f*w), sh = sinf(0.5f*w);                \
                const Cpx RX[2][2] = {{{ch,0.f},{0.f,-sh}},{{0.f,-sh},{ch,0.f}}};\
                const Cpx RZ[2][2] = {{{ch,-sh},{0.f,0.f}},{{0.f,0.f},{ch,sh}}};\
                Cpx T[2][2], A[2][2];                                            \
                for (int i = 0; i < 2; ++i)                                      \
                    for (int j = 0; j < 2; ++j) {                                \
                        Cpx s{0.f,0.f};                                          \
                        for (int k = 0; k < 2; ++k)                              \
                            s = cadd(s, cmul(RZ[i][k], RX[k][j]));               \
                        T[i][j] = s;                                             \
                    }                                                            \
                for (int i = 0; i < 2; ++i)                                      \
                    for (int j = 0; j < 2; ++j) {                                \
                        Cpx s{0.f,0.f};                                          \
                        for (int k = 0; k < 2; ++k)                              \
                            s = cadd(s, cmul(RX[i][k], T[k][j]));                \
                        A[i][j] = s;                                             \
                    }                                                            \
                _Pragma("unroll")                                                \
                for (int r = 0; r < 16; ++r) {                                   \
                    if (r & (BIT)) continue;                                     \
                    const int r1 = r | (BIT);                                    \
                    Cpx a0 = col[r], a1 = col[r1];                               \
                    col[r]  = cadd(cmul(A[0][0], a0), cmul(A[0][1], a1));        \
                    col[r1] = cadd(cmul(A[1][0], a0), cmul(A[1][1], a1));        \
                }                                                                \
            }
            APPLY_Q(0, 8)
            APPLY_Q(1, 4)
            APPLY_Q(2, 2)
            APPLY_Q(3, 1)
            #undef APPLY_Q

            // entangler ring: CNOT(c,t) RZ(th,t) CNOT(c,t) == diagonal phase:
            // e^{-i th/2} if bit_c==bit_t else e^{+i th/2}
            for (int e = 0; e < 4; ++e) {
                const int c = e, t = (e + 1) & 3;
                const float th = qw[l*4 + t];
                const float ch = cosf(0.5f*th), sh = sinf(0.5f*th);
                const Cpx pe{ch,-sh}, pd{ch,sh};
                const int bc = 1 << (3 - c), bt = 1 << (3 - t);
                #pragma unroll
                for (int r = 0; r < 16; ++r) {
                    const bool eq = (((r & bc) != 0) == ((r & bt) != 0));
                    col[r] = cmul(eq ? pe : pd, col[r]);
                }
            }
        }
        #pragma unroll
        for (int i = 0; i < 16; ++i) U[i][tid] = col[i];
    }
    __syncthreads();

    // ---- M_k = U^dag Z_k U ----
    for (int e = tid; e < 4*16*16; e += blockDim.x) {
        const int k = e >> 8, i = (e >> 4) & 15, j = e & 15;
        const int kb = 1 << (3 - k);
        Cpx s{0.f,0.f};
        for (int m = 0; m < 16; ++m) {
            const float sg = (m & kb) ? -1.f : 1.f;
            Cpx um = U[m][i]; um.y = -um.y;        // conj
            Cpx t  = cmul(um, U[m][j]);
            s.x += sg * t.x; s.y += sg * t.y;
        }
        M[k][i][j] = s;
    }
    __syncthreads();

    // ---- C[k][a] = Re Tr(P_a M_k)/16 * (-1)^{#Y}; digit q (3^q): 0=I,1=Z,2=Y
    for (int e = tid; e < 4*81; e += blockDim.x) {
        const int k = e / 81, a = e % 81;
        int d[4], aa = a;
        for (int q = 0; q < 4; ++q) { d[q] = aa % 3; aa /= 3; }
        int ym = 0, ny = 0;
        for (int q = 0; q < 4; ++q) if (d[q] == 2) { ym |= 1 << (3 - q); ++ny; }
        Cpx tr{0.f,0.f};
        for (int i = 0; i < 16; ++i) {
            const int j = i ^ ym;                   // P[i][j] nonzero only here
            Cpx p{1.f,0.f};
            for (int q = 0; q < 4; ++q) {
                const int bi = (i >> (3 - q)) & 1;
                if (d[q] == 1) { if (bi) { p.x = -p.x; p.y = -p.y; } }
                else if (d[q] == 2) {
                    Cpx f = bi ? Cpx{0.f,1.f} : Cpx{0.f,-1.f};  // sigma_y
                    p = cmul(p, f);
                }
            }
            tr = cadd(tr, cmul(p, M[k][j][i]));
        }
        float val = tr.x * 0.0625f;
        if (ny & 1) val = -val;
        C[k*81 + a] = val;
    }
}

// ---------------------------------------------------------------------------
// Main: 32 lanes per sample, 2 samples per wave, 4 waves (8 samples) / block.
// sl = lane & 31. Lane owns h[sl + 32j] j=0..3 and x_t[2sl..2sl+1].
// reduce1: fold (dpp xor1, dpp xor2) -> comp kown=sl&3, then ds_swizzle
//          xor4/8/16, then 4 dpp quad-broadcasts -> y0..y3.
// z-Horner: grp=sl>>2 handles (d2,d3) combo c=grp (grp0 also combo 8);
//           two 9-coeff Horners + one-hot (d2,d3) factors.
// reduce2: ds_swizzle xor4/8/16 + 4 dpp quad-broadcasts.
// ---------------------------------------------------------------------------

__global__ __launch_bounds__(256, 4) void qrnn_main(
    const float* __restrict__ x,
    const float* __restrict__ W_in,
    const float* __restrict__ b_in,
    const float* __restrict__ W_out,
    const float* __restrict__ b_out,
    const float* __restrict__ C,
    float* __restrict__ out,
    int B)
{
    const int lane = threadIdx.x & 63;
    const int wv   = threadIdx.x >> 6;
    const int slot = lane >> 5;          // sample within wave (0/1)
    const int sl   = lane & 31;          // lane within sample group
    const int b    = blockIdx.x * 8 + wv * 2 + slot;
    const int bc   = (b < B) ? b : (B - 1);

    // ---- per-lane constants ----------------------------------------------
    // W_in rows (q=0..3, row len 192 = [h(128); x(64)])
    float wa[4][4], wx[4][2];
    #pragma unroll
    for (int q = 0; q < 4; ++q) {
        #pragma unroll
        for (int j = 0; j < 4; ++j) wa[q][j] = W_in[q*192 + sl + 32*j];
        wx[q][0] = W_in[q*192 + 128 + 2*sl];
        wx[q][1] = W_in[q*192 + 128 + 2*sl + 1];
    }
    const int kown = sl & 3;             // owned component
    const int grp  = sl >> 2;            // combo group 0..7
    const float bi_own = b_in[kown];

    // combo c = grp: d3 = c/3, d2 = c%3; grp0 additionally combo 8 (d3=d2=2)
    const int d3 = grp / 3, d2 = grp % 3;
    float cc0[9], cc1[9];
    #pragma unroll
    for (int m = 0; m < 9; ++m) {
        cc0[m] = C[kown*81 + 27*d3 + 9*d2 + m];
        cc1[m] = (grp == 0) ? C[kown*81 + 72 + m] : 0.f;
    }
    // one-hot selectors for g2(d2), g3(d3): f = oi + oc*cos + os*sin
    const float o2i = (d2 == 0) ? 1.f : 0.f, o2c = (d2 == 1) ? 1.f : 0.f,
                o2s = (d2 == 2) ? 1.f : 0.f;
    const float o3i = (d3 == 0) ? 1.f : 0.f, o3c = (d3 == 1) ? 1.f : 0.f,
                o3s = (d3 == 2) ? 1.f : 0.f;

    // W_out rows r = sl + 32j
    float wo[4][4], bo[4];
    #pragma unroll
    for (int j = 0; j < 4; ++j) {
        #pragma unroll
        for (int k = 0; k < 4; ++k) wo[j][k] = W_out[(sl + 32*j)*4 + k];
        bo[j] = b_out[sl + 32*j];
    }

    // ---- state ------------------------------------------------------------
    float h[4];
    #pragma unroll
    for (int j = 0; j < 4; ++j) h[j] = 0.f;

    const float* __restrict__ xb = x + (size_t)bc * (128*64) + 2*sl;
    float2 xcur = *(const float2*)(xb);          // t = 0
    float2 xnxt = *(const float2*)(xb + 64);     // t = 1

    for (int t = 0; t < 128; ++t) {
        const int tp = (t + 2 < 128) ? (t + 2) : 127;
        const float2 xpre = *(const float2*)(xb + tp*64);

        // ---- y partials
        float p0, p1, p2, p3;
        p0 = wx[0][0]*xcur.x; p1 = wx[1][0]*xcur.x;
        p2 = wx[2][0]*xcur.x; p3 = wx[3][0]*xcur.x;
        p0 = fmaf(wx[0][1], xcur.y, p0); p1 = fmaf(wx[1][1], xcur.y, p1);
        p2 = fmaf(wx[2][1], xcur.y, p2); p3 = fmaf(wx[3][1], xcur.y, p3);
        #pragma unroll
        for (int j = 0; j < 4; ++j) {
            p0 = fmaf(wa[0][j], h[j], p0);
            p1 = fmaf(wa[1][j], h[j], p1);
            p2 = fmaf(wa[2][j], h[j], p2);
            p3 = fmaf(wa[3][j], h[j], p3);
        }

        // ---- reduce1: fold to comp kown over the 32-lane group
        float yown;
        {
            const bool o1 = (sl & 1) != 0;
            const bool o2 = (sl & 2) != 0;
            // stage 1: xor1 via DPP quad_perm [1,0,3,2] = 0xB1
            float sendA = o1 ? p0 : p1;
            float a  = (o1 ? p1 : p0) + fdpp<0xB1>(sendA);
            float sendB = o1 ? p2 : p3;
            float bq = (o1 ? p3 : p2) + fdpp<0xB1>(sendB);
            // stage 2: xor2 via DPP quad_perm [2,3,0,1] = 0x4E
            float send2 = o2 ? a : bq;
            float s  = (o2 ? bq : a) + fdpp<0x4E>(send2);
            // butterfly xor4/8/16 via ds_swizzle BitMode
            s += fswz<0x101F>(s);
            s += fswz<0x201F>(s);
            s += fswz<0x401F>(s);
            yown = s + bi_own;
        }
        // quad broadcasts via DPP: y_q lives on lane (lane&~3)|q
        const float y0 = fdpp<0x00>(yown);
        const float y1 = fdpp<0x55>(yown);
        const float y2 = fdpp<0xAA>(yown);
        const float y3 = fdpp<0xFF>(yown);

        float s0, c0, s1, c1, s2, c2, s3, c3;
        __sincosf(y0, &s0, &c0);
        __sincosf(y1, &s1, &c1);
        __sincosf(y2, &s2, &c2);
        __sincosf(y3, &s3, &c3);

        // ---- z-Horner: combo factors + two 9-coeff Horners
        const float f2  = fmaf(o2c, c2, fmaf(o2s, s2, o2i));
        const float f3  = fmaf(o3c, c3, fmaf(o3s, s3, o3i));
        const float f23 = f2 * f3;
        const float f8  = s2 * s3;                 // combo 8 factor
        float i0, i1;
        {
            float t0 = fmaf(s0, cc0[2], fmaf(c0, cc0[1], cc0[0]));
            float t1 = fmaf(s0, cc0[5], fmaf(c0, cc0[4], cc0[3]));
            float t2 = fmaf(s0, cc0[8], fmaf(c0, cc0[7], cc0[6]));
            i0 = fmaf(s1, t2, fmaf(c1, t1, t0));
            t0 = fmaf(s0, cc1[2], fmaf(c0, cc1[1], cc1[0]));
            t1 = fmaf(s0, cc1[5], fmaf(c0, cc1[4], cc1[3]));
            t2 = fmaf(s0, cc1[8], fmaf(c0, cc1[7], cc1[6]));
            i1 = fmaf(s1, t2, fmaf(c1, t1, t0));
        }
        float zp = fmaf(f23, i0, f8 * i1);

        // ---- reduce2: sum zp over the 8 grps sharing kown
        zp += fswz<0x101F>(zp);
        zp += fswz<0x201F>(zp);
        zp += fswz<0x401F>(zp);
        const float z0 = fdpp<0x00>(zp);
        const float z1 = fdpp<0x55>(zp);
        const float z2 = fdpp<0xAA>(zp);
        const float z3 = fdpp<0xFF>(zp);

        // ---- output proj + sigmoid
        #pragma unroll
        for (int j = 0; j < 4; ++j) {
            float u = fmaf(wo[j][0], z0, fmaf(wo[j][1], z1,
                      fmaf(wo[j][2], z2, fmaf(wo[j][3], z3, bo[j]))));
            h[j] = 1.f / (1.f + __expf(-u));
        }

        xcur = xnxt; xnxt = xpre;
    }

    if (b < B) {
        float* ob = out + (size_t)b * 128 + sl;
        #pragma unroll
        for (int j = 0; j < 4; ++j) ob[32*j] = h[j];
    }
}

extern "C" void kernel_launch(void* const* d_in, const int* in_sizes, int n_in,
                              void* d_out, int out_size, void* d_ws, size_t ws_size,
                              hipStream_t stream)
{
    const float* x     = (const float*)d_in[0];
    const float* W_in  = (const float*)d_in[1];
    const float* b_in  = (const float*)d_in[2];
    const float* qw    = (const float*)d_in[3];
    const float* W_out = (const float*)d_in[4];
    const float* b_out = (const float*)d_in[5];
    float* out = (float*)d_out;
    float* C   = (float*)d_ws;                 // 4*81 floats

    const int B = in_sizes[0] / (128*64);      // 8192

    qrnn_precompute<<<1, 64, 0, stream>>>(qw, C);
    const int blocks = (B + 7) / 8;            // 8 samples per 256-thread block
    qrnn_main<<<blocks, 256, 0, stream>>>(x, W_in, b_in, W_out, b_out, C, out, B);
}